// Round 1
// 1389.754 us; speedup vs baseline: 1.1545x; 1.1545x over previous
//
#include <hip/hip_runtime.h>
#include <stdint.h>

#define LSEG 8
#define NCAND 7168
#define SLEN 256
#define MAXW 30
#define KOUT 128
#define DEMB 2304
#define DHID 150
#define PADV (SLEN + MAXW + 1) /* 287 */

#define MTILE 112
#define NPAD 160
#define KT 32

// ---------------------------------------------------------------------------
// async global->LDS 16B helper (linear LDS dest; swizzle applied on SOURCE)
// ---------------------------------------------------------------------------
typedef const unsigned int __attribute__((address_space(1)))* gp_t;
typedef unsigned int __attribute__((address_space(3)))* lp_t;

__device__ __forceinline__ void gload16(const float* g, float* l) {
    __builtin_amdgcn_global_load_lds((gp_t)g, (lp_t)l, 16, 0, 0);
}

// ---------------------------------------------------------------------------
// Kernel 0: transpose W1 [2304][150] -> W1T [150][2304] (coalesced writes)
// ---------------------------------------------------------------------------
__global__ __launch_bounds__(256) void k_transpose(const float* __restrict__ w1,
                                                   float* __restrict__ w1t) {
    int i = blockIdx.x * 256 + threadIdx.x;  // over 150*2304 = 345600
    if (i < DHID * DEMB) {
        int n = i / DEMB;
        int k = i - n * DEMB;
        w1t[i] = w1[k * DHID + n];
    }
}

// ---------------------------------------------------------------------------
// Kernel 1: scores[m] = W2 . relu(W1^T emb[m] + b1) + b2  for m in [0,57344)
// Block tile: 112 rows x 160 cols (150 padded), K-tile 32.
// Grid = 57344/112 = 512 = exactly 2 blocks/CU (34.8 KB LDS) -> perfect balance.
// Staging: global_load_lds dwordx4, LDS linear, XOR chunk-swizzle (c ^= row&7)
// on global source + LDS read (involution): av reads conflict-free, wv 2-way.
// FMA order identical to previous kernel (k ascending, x..w) -> bitwise-same.
// ---------------------------------------------------------------------------
__global__ __launch_bounds__(256, 2) void k_scores(
    const float* __restrict__ emb, const float* __restrict__ w1t,
    const float* __restrict__ b1, const float* __restrict__ w2,
    const float* __restrict__ b2, float* __restrict__ scores) {
    __shared__ float smem[(MTILE + NPAD) * KT];  // 8704 floats = 34816 B
    float* amem = smem;               // [112][32] swizzled chunks
    float* wmem = smem + MTILE * KT;  // [160][32] swizzled chunks (150..159 zero)

    const int tid = threadIdx.x;
    const int tx = tid & 15;
    const int ty = tid >> 4;
    const int M0 = blockIdx.x * MTILE;

    // zero padded W rows 150..159 once (never touched by staging)
    for (int u = tid; u < (NPAD - DHID) * KT; u += 256) wmem[DHID * KT + u] = 0.f;

    float acc[7][10];
#pragma unroll
    for (int i = 0; i < 7; ++i)
#pragma unroll
        for (int j = 0; j < 10; ++j) acc[i][j] = 0.f;

    for (int k0 = 0; k0 < DEMB; k0 += KT) {
        // stage A: 112*8 = 896 16B chunks (async -> LDS, source-swizzled)
#pragma unroll
        for (int r = 0; r < 4; ++r) {
            int u = tid + 256 * r;
            if (u < MTILE * 8) {
                int row = u >> 3, cd = u & 7;
                int gc = cd ^ (row & 7);
                gload16(emb + (size_t)(M0 + row) * DEMB + k0 + gc * 4, amem + u * 4);
            }
        }
        // stage W: 150*8 = 1200 chunks
#pragma unroll
        for (int r = 0; r < 5; ++r) {
            int u = tid + 256 * r;
            if (u < DHID * 8) {
                int row = u >> 3, cd = u & 7;
                int gc = cd ^ (row & 7);
                gload16(w1t + (size_t)row * DEMB + k0 + gc * 4, wmem + u * 4);
            }
        }
        __syncthreads();  // vmcnt drain + barrier: tile ready

#pragma unroll 2
        for (int kc = 0; kc < 8; ++kc) {
            float4 av[7];
            float4 wv[10];
#pragma unroll
            for (int i = 0; i < 7; ++i) {
                int row = ty * 7 + i;
                av[i] = *(const float4*)(amem + row * KT + ((kc ^ (row & 7)) << 2));
            }
#pragma unroll
            for (int j = 0; j < 10; ++j) {
                int n = tx + 16 * j;
                wv[j] = *(const float4*)(wmem + n * KT + ((kc ^ (tx & 7)) << 2));
            }
#pragma unroll
            for (int i = 0; i < 7; ++i) {
#pragma unroll
                for (int j = 0; j < 10; ++j) {
                    acc[i][j] += av[i].x * wv[j].x;
                    acc[i][j] += av[i].y * wv[j].y;
                    acc[i][j] += av[i].z * wv[j].z;
                    acc[i][j] += av[i].w * wv[j].w;
                }
            }
        }
        __syncthreads();  // all reads done before next-tile overwrite
    }

    // epilogue: h = relu(z + b1), partial score = sum_n h * w2  (same order as v1)
    float partial[7];
#pragma unroll
    for (int i = 0; i < 7; ++i) partial[i] = 0.f;
#pragma unroll
    for (int j = 0; j < 10; ++j) {
        int n = tx + 16 * j;
        float bb = (n < DHID) ? b1[n] : 0.f;
        float ww = (n < DHID) ? w2[n] : 0.f;
#pragma unroll
        for (int i = 0; i < 7; ++i) {
            float h = acc[i][j] + bb;
            h = fmaxf(h, 0.f);
            partial[i] += h * ww;
        }
    }
    // reduce 16 partials per row via LDS (reuse amem region; safe after loop-end sync)
    float* red = smem;  // [112][17]
#pragma unroll
    for (int i = 0; i < 7; ++i) red[(ty * 7 + i) * 17 + tx] = partial[i];
    __syncthreads();
    if (tid < MTILE) {
        float sacc = 0.f;
#pragma unroll
        for (int t = 0; t < 16; ++t) sacc += red[tid * 17 + t];
        scores[M0 + tid] = sacc + b2[0];
    }
}

// ---------------------------------------------------------------------------
// Kernel 2: per-segment: stable sort by (-score, idx), CHUNKED greedy
// non-crossing selection (64 candidates per serial round; exact semantics),
// re-sort selected by (start,end,slot), emit.
// NOTE: indices emitted as FLOAT values (harness reads d_out as float32).
// ---------------------------------------------------------------------------
__global__ __launch_bounds__(1024) void k_extract(
    const float* __restrict__ scores,
    const int* __restrict__ cs, const int* __restrict__ ce,
    float* __restrict__ out_sc, float* __restrict__ out_idx) {
    __shared__ unsigned ks[8192];        // 32 KB: sort key, later packed (s,e)
    __shared__ unsigned short id[8192];  // 16 KB: candidate index payload
    __shared__ int le[352];              // latest_end
    __shared__ int es[352];              // earliest_start
    __shared__ int sel_idx[KOUT];
    __shared__ unsigned sel_se[KOUT];
    __shared__ unsigned skey[KOUT];
    __shared__ int nshare;

    const int tid = threadIdx.x;
    const int l = blockIdx.x;
    const int base = l * NCAND;

    for (int i = tid; i < 352; i += 1024) { le[i] = -1; es[i] = PADV; }
    if (tid < KOUT) { sel_idx[tid] = 0; sel_se[tid] = 0; }

    // fill keys: ascending key == descending score, tie -> ascending idx
    for (int t = tid; t < 8192; t += 1024) {
        if (t < NCAND) {
            unsigned u = __float_as_uint(scores[base + t]);
            u = (u & 0x80000000u) ? ~u : (u | 0x80000000u);  // total-order asc
            ks[t] = ~u;                                      // descending
            id[t] = (unsigned short)t;
        } else {
            ks[t] = 0xFFFFFFFFu;
            id[t] = 0xFFFFu;
        }
    }

    // bitonic sort ascending over (ks, id) lexicographic
    for (int k = 2; k <= 8192; k <<= 1) {
        for (int j = k >> 1; j > 0; j >>= 1) {
            __syncthreads();
            for (int t = tid; t < 8192; t += 1024) {
                int p = t ^ j;
                if (p > t) {
                    unsigned ka = ks[t], kb = ks[p];
                    unsigned short ia = id[t], ib = id[p];
                    bool agtb = (ka > kb) || (ka == kb && ia > ib);
                    bool up = ((t & k) == 0);
                    if (agtb == up) {
                        ks[t] = kb; ks[p] = ka;
                        id[t] = ib; id[p] = ia;
                    }
                }
            }
        }
    }
    __syncthreads();

    // repack ks[t] = start | (end<<16), in sorted order (keeps greedy LDS-only)
    for (int t = tid; t < NCAND; t += 1024) {
        int i0 = id[t];
        ks[t] = (unsigned)cs[base + i0] | ((unsigned)ce[base + i0] << 16);
    }
    __syncthreads();

    // ---- chunked greedy: wave 0, 64 candidates per round --------------------
    // Exact equivalence to sequential greedy:
    //  - state check (le/es) covers spans selected in PREVIOUS chunks
    //  - intra-chunk interactions resolved serially with the exact symmetric
    //    pairwise crossing predicate against the 'taken' mask
    if (tid < 64) {
        volatile int* lev = le;
        volatile int* esv = es;
        const int lane = tid;
        int n = 0;
        for (int t0 = 0; t0 < NCAND && n < KOUT; t0 += 64) {
            const int t = t0 + lane;  // NCAND = 112*64: always valid
            const unsigned se = ks[t];
            const int s = (int)(se & 0xFFFFu);
            const int e = (int)(se >> 16);
            const int w = e - s;
            // state check vs previously selected spans
            bool cr = false;
#pragma unroll
            for (int ro = 0; ro <= MAXW; ++ro) {
                int lv = lev[s + ro];
                int ev = esv[s + ro];
                cr = cr || ((ro >= 1) && (ro <= w) && (lv > e));  // j in (s,e]
                cr = cr || ((ro < w) && (ev < s));                // j in [s,e)
            }
            unsigned long long ok = __ballot(!cr);
            unsigned long long taken = 0ull;
            const int nbase = n;
            while (ok) {
                int j = __builtin_ctzll(ok);
                ok &= ok - 1ull;
                int sj = __shfl(s, j);
                int ej = __shfl(e, j);
                // symmetric partial-overlap (crossing) of my span vs span j
                bool crj = (s < sj && sj <= e && e < ej) ||
                           (sj < s && s <= ej && ej < e);
                unsigned long long cm = __ballot(crj);
                if ((cm & taken) == 0ull) {
                    taken |= (1ull << j);
                    ++n;
                    if (n >= KOUT) break;
                }
            }
            if ((taken >> lane) & 1ull) {
                int slot = nbase + __popcll(taken & ((1ull << lane) - 1ull));
                sel_idx[slot] = (int)id[t];
                sel_se[slot] = se;
                atomicMax(&le[s], e);
                atomicMin(&es[e], s);
            }
            __threadfence_block();  // updates visible to next chunk's reads
        }
        if (lane == 0) nshare = n;
    }
    __syncthreads();

    const int nsel = nshare;
    // build final sort keys: (start*287+end)<<7 | slot (stable on ties)
    if (tid < KOUT) {
        if (tid < nsel) {
            unsigned se = sel_se[tid];
            int s = (int)(se & 0xFFFFu);
            int e = (int)(se >> 16);
            skey[tid] = ((unsigned)(s * PADV + e) << 7) | (unsigned)tid;
        } else {
            skey[tid] = 0x7F000000u | (unsigned)tid;
        }
    }
    // bitonic 128 ascending
    for (int k = 2; k <= KOUT; k <<= 1) {
        for (int j = k >> 1; j > 0; j >>= 1) {
            __syncthreads();
            if (tid < KOUT) {
                int t = tid, p = t ^ j;
                if (p > t) {
                    unsigned a = skey[t], b = skey[p];
                    bool up = ((t & k) == 0);
                    if ((a > b) == up) { skey[t] = b; skey[p] = a; }
                }
            }
        }
    }
    __syncthreads();
    if (tid < KOUT) {
        int oslot = (int)(skey[tid] & 127u);
        int slot0 = (int)(skey[0] & 127u);
        int oi = (tid < nsel) ? sel_idx[oslot] : sel_idx[slot0];
        out_idx[l * KOUT + tid] = (float)oi;   // harness reads d_out as float32
        out_sc[l * KOUT + tid] = scores[base + oi];
    }
}

// ---------------------------------------------------------------------------
extern "C" void kernel_launch(void* const* d_in, const int* in_sizes, int n_in,
                              void* d_out, int out_size, void* d_ws, size_t ws_size,
                              hipStream_t stream) {
    const float* emb = (const float*)d_in[0];
    const float* w1  = (const float*)d_in[1];
    const float* b1  = (const float*)d_in[2];
    const float* w2  = (const float*)d_in[3];
    const float* b2  = (const float*)d_in[4];
    const int*   cs  = (const int*)d_in[5];
    const int*   ce  = (const int*)d_in[6];

    float* ws_scores = (float*)d_ws;                    // 57344 floats (229 KB)
    float* ws_w1t    = (float*)((char*)d_ws + 262144);  // 150*2304 floats (1.35 MB)

    k_transpose<<<dim3(1350), dim3(256), 0, stream>>>(w1, ws_w1t);
    k_scores<<<dim3((LSEG * NCAND) / MTILE), dim3(256), 0, stream>>>(
        emb, ws_w1t, b1, w2, b2, ws_scores);
    k_extract<<<dim3(LSEG), dim3(1024), 0, stream>>>(
        ws_scores, cs, ce, (float*)d_out, (float*)d_out + LSEG * KOUT);
}

// Round 2
// 1360.040 us; speedup vs baseline: 1.1798x; 1.0218x over previous
//
#include <hip/hip_runtime.h>
#include <stdint.h>

#define LSEG 8
#define NCAND 7168
#define SLEN 256
#define MAXW 30
#define KOUT 128
#define DEMB 2304
#define DHID 150
#define PADV (SLEN + MAXW + 1) /* 287 */

#define MTILE 112
#define NPAD 160
#define KT 16
#define BUF ((MTILE + NPAD) * KT) /* 4352 floats per buffer */

// ---------------------------------------------------------------------------
// async global->LDS 16B helper (linear LDS dest; swizzle applied on SOURCE)
// ---------------------------------------------------------------------------
typedef const unsigned int __attribute__((address_space(1)))* gp_t;
typedef unsigned int __attribute__((address_space(3)))* lp_t;

__device__ __forceinline__ void gload16(const float* g, float* l) {
    __builtin_amdgcn_global_load_lds((gp_t)g, (lp_t)l, 16, 0, 0);
}

// ---------------------------------------------------------------------------
// Kernel 0: transpose W1 [2304][150] -> W1T [150][2304] (coalesced writes)
// ---------------------------------------------------------------------------
__global__ __launch_bounds__(256) void k_transpose(const float* __restrict__ w1,
                                                   float* __restrict__ w1t) {
    int i = blockIdx.x * 256 + threadIdx.x;  // over 150*2304 = 345600
    if (i < DHID * DEMB) {
        int n = i / DEMB;
        int k = i - n * DEMB;
        w1t[i] = w1[k * DHID + n];
    }
}

// ---------------------------------------------------------------------------
// Kernel 1: scores[m] = W2 . relu(W1^T emb[m] + b1) + b2  for m in [0,57344)
// Block tile 112 x 160(150p), K-tile 16, DOUBLE-BUFFERED LDS (2x17.4KB).
// 2-phase pipeline: stage(t+1) issued before compute(t); the syncthreads
// vmcnt(0) drain then waits on loads that had a full compute phase to land.
// Swizzle: chunk-of-4-floats gc = cd ^ ((row>>1)&3) applied on global SOURCE
// and LDS READ (XOR involution, linear LDS dest as global_load_lds requires).
// av reads conflict-free; wv reads 2-way (free, m136).
// FMA order: k strictly ascending per acc chain (k0 asc, kc asc, x..w) ->
// bitwise-identical scores to previous rounds.
// ---------------------------------------------------------------------------
__global__ __launch_bounds__(256, 2) void k_scores(
    const float* __restrict__ emb, const float* __restrict__ w1t,
    const float* __restrict__ b1, const float* __restrict__ w2,
    const float* __restrict__ b2, float* __restrict__ scores) {
    __shared__ float smem[2 * BUF];  // 34816 B

    const int tid = threadIdx.x;
    const int tx = tid & 15;
    const int ty = tid >> 4;
    const int M0 = blockIdx.x * MTILE;

    // precomputed stage pointers: u = tid + 256*r; row = u>>2; cd = u&3;
    // gc = cd ^ ((u>>3)&3)  (invariant across r since 256/8 % 4 == 0)
    const int gc = (tid & 3) ^ ((tid >> 3) & 3);
    const int arow = tid >> 2;  // 0..63
    const float* gA0 = emb + (size_t)(M0 + arow) * DEMB + gc * 4;
    const float* gA1 = gA0 + (size_t)64 * DEMB;   // rows 64..111 (tid<192)
    const float* gW0 = w1t + (size_t)arow * DEMB + gc * 4;
    const float* gW1 = gW0 + (size_t)64 * DEMB;   // rows 64..127
    const float* gW2 = gW0 + (size_t)128 * DEMB;  // rows 128..149 (tid<88)
    const bool has_a1 = (tid < 192);
    const bool has_w2 = (tid < 88);

    // zero padded W rows 150..159 in BOTH buffers (never staged)
    if (tid < NPAD) {
        smem[(MTILE + DHID) * KT + tid] = 0.f;
        smem[BUF + (MTILE + DHID) * KT + tid] = 0.f;
    }

    float acc[7][10];
#pragma unroll
    for (int i = 0; i < 7; ++i)
#pragma unroll
        for (int j = 0; j < 10; ++j) acc[i][j] = 0.f;

    const int NT = DEMB / KT;  // 144 tiles

    // prologue: stage tile 0 into buffer 0
    {
        float* am = smem;
        float* wm = smem + MTILE * KT;
        gload16(gA0, am + tid * 4);
        if (has_a1) gload16(gA1, am + (tid + 256) * 4);
        gload16(gW0, wm + tid * 4);
        gload16(gW1, wm + (tid + 256) * 4);
        if (has_w2) gload16(gW2, wm + (tid + 512) * 4);
    }
    __syncthreads();  // vmcnt(0) drain: tile 0 ready

    const int wsw = (tx >> 1) & 3;  // W-read swizzle base (row>>1)&3 for n=tx+16j

    for (int t = 0; t < NT; ++t) {
        const int cur = t & 1;
        // issue next tile's stage into the other buffer (no wait here)
        if (t + 1 < NT) {
            float* am = smem + (cur ^ 1) * BUF;
            float* wm = am + MTILE * KT;
            const int ko = (t + 1) * KT;
            gload16(gA0 + ko, am + tid * 4);
            if (has_a1) gload16(gA1 + ko, am + (tid + 256) * 4);
            gload16(gW0 + ko, wm + tid * 4);
            gload16(gW1 + ko, wm + (tid + 256) * 4);
            if (has_w2) gload16(gW2 + ko, wm + (tid + 512) * 4);
        }
        // compute current tile
        const float* am = smem + cur * BUF;
        const float* wm = am + MTILE * KT;
#pragma unroll
        for (int kc = 0; kc < 4; ++kc) {
            float4 av[7];
            float4 wv[10];
#pragma unroll
            for (int i = 0; i < 7; ++i) {
                int row = ty * 7 + i;
                av[i] = *(const float4*)(am + row * KT +
                                         ((kc ^ ((row >> 1) & 3)) << 2));
            }
#pragma unroll
            for (int j = 0; j < 10; ++j) {
                int n = tx + 16 * j;
                wv[j] = *(const float4*)(wm + n * KT + ((kc ^ wsw) << 2));
            }
#pragma unroll
            for (int i = 0; i < 7; ++i) {
#pragma unroll
                for (int j = 0; j < 10; ++j) {
                    acc[i][j] += av[i].x * wv[j].x;
                    acc[i][j] += av[i].y * wv[j].y;
                    acc[i][j] += av[i].z * wv[j].z;
                    acc[i][j] += av[i].w * wv[j].w;
                }
            }
        }
        __syncthreads();  // drains vmcnt(0) (next tile landed during compute),
                          // lgkmcnt(0), and protects buffer reuse
    }

    // epilogue: h = relu(z + b1), partial score = sum_n h * w2 (same order)
    float partial[7];
#pragma unroll
    for (int i = 0; i < 7; ++i) partial[i] = 0.f;
#pragma unroll
    for (int j = 0; j < 10; ++j) {
        int n = tx + 16 * j;
        float bb = (n < DHID) ? b1[n] : 0.f;
        float ww = (n < DHID) ? w2[n] : 0.f;
#pragma unroll
        for (int i = 0; i < 7; ++i) {
            float h = acc[i][j] + bb;
            h = fmaxf(h, 0.f);
            partial[i] += h * ww;
        }
    }
    // reduce 16 partials per row via LDS (reuse smem; all compute synced)
    float* red = smem;  // [112][17]
#pragma unroll
    for (int i = 0; i < 7; ++i) red[(ty * 7 + i) * 17 + tx] = partial[i];
    __syncthreads();
    if (tid < MTILE) {
        float sacc = 0.f;
#pragma unroll
        for (int t = 0; t < 16; ++t) sacc += red[tid * 17 + t];
        scores[M0 + tid] = sacc + b2[0];
    }
}

// ---------------------------------------------------------------------------
// Kernel 2: per-segment: stable sort by (-score, idx), CHUNKED greedy
// non-crossing selection (64 candidates per round; exact semantics; NO
// volatile — wave-0-only state with __threadfence_block ordering),
// re-sort selected by (start,end,slot), emit.
// NOTE: indices emitted as FLOAT values (harness reads d_out as float32).
// ---------------------------------------------------------------------------
__global__ __launch_bounds__(1024) void k_extract(
    const float* __restrict__ scores,
    const int* __restrict__ cs, const int* __restrict__ ce,
    float* __restrict__ out_sc, float* __restrict__ out_idx) {
    __shared__ unsigned ks[8192];        // 32 KB: sort key, later packed (s,e)
    __shared__ unsigned short id[8192];  // 16 KB: candidate index payload
    __shared__ int le[352];              // latest_end
    __shared__ int es[352];              // earliest_start
    __shared__ int sel_idx[KOUT];
    __shared__ unsigned sel_se[KOUT];
    __shared__ unsigned skey[KOUT];
    __shared__ int nshare;

    const int tid = threadIdx.x;
    const int l = blockIdx.x;
    const int base = l * NCAND;

    for (int i = tid; i < 352; i += 1024) { le[i] = -1; es[i] = PADV; }
    if (tid < KOUT) { sel_idx[tid] = 0; sel_se[tid] = 0; }

    // fill keys: ascending key == descending score, tie -> ascending idx
    for (int t = tid; t < 8192; t += 1024) {
        if (t < NCAND) {
            unsigned u = __float_as_uint(scores[base + t]);
            u = (u & 0x80000000u) ? ~u : (u | 0x80000000u);  // total-order asc
            ks[t] = ~u;                                      // descending
            id[t] = (unsigned short)t;
        } else {
            ks[t] = 0xFFFFFFFFu;
            id[t] = 0xFFFFu;
        }
    }

    // bitonic sort ascending over (ks, id) lexicographic
    for (int k = 2; k <= 8192; k <<= 1) {
        for (int j = k >> 1; j > 0; j >>= 1) {
            __syncthreads();
            for (int t = tid; t < 8192; t += 1024) {
                int p = t ^ j;
                if (p > t) {
                    unsigned ka = ks[t], kb = ks[p];
                    unsigned short ia = id[t], ib = id[p];
                    bool agtb = (ka > kb) || (ka == kb && ia > ib);
                    bool up = ((t & k) == 0);
                    if (agtb == up) {
                        ks[t] = kb; ks[p] = ka;
                        id[t] = ib; id[p] = ia;
                    }
                }
            }
        }
    }
    __syncthreads();

    // repack ks[t] = start | (end<<16), in sorted order (keeps greedy LDS-only)
    for (int t = tid; t < NCAND; t += 1024) {
        int i0 = id[t];
        ks[t] = (unsigned)cs[base + i0] | ((unsigned)ce[base + i0] << 16);
    }
    __syncthreads();

    // ---- chunked greedy: wave 0, 64 candidates per round --------------------
    // Exact equivalence to sequential greedy:
    //  - state check (le/es) covers spans selected in PREVIOUS chunks
    //  - intra-chunk interactions resolved serially with the exact symmetric
    //    pairwise crossing predicate against the 'taken' mask
    if (tid < 64) {
        const int lane = tid;
        int n = 0;
        for (int t0 = 0; t0 < NCAND && n < KOUT; t0 += 64) {
            const int t = t0 + lane;  // NCAND = 112*64: always valid
            const unsigned se = ks[t];
            const int s = (int)(se & 0xFFFFu);
            const int e = (int)(se >> 16);
            const int w = e - s;
            // state check vs previously selected spans (plain LDS reads;
            // ordering vs prior chunk's updates via __threadfence_block)
            bool cr = false;
#pragma unroll
            for (int ro = 0; ro <= MAXW; ++ro) {
                int lv = le[s + ro];
                int ev = es[s + ro];
                cr = cr || ((ro >= 1) && (ro <= w) && (lv > e));  // j in (s,e]
                cr = cr || ((ro < w) && (ev < s));                // j in [s,e)
            }
            unsigned long long ok = __ballot(!cr);
            unsigned long long taken = 0ull;
            const int nbase = n;
            while (ok) {
                int j = __builtin_ctzll(ok);
                ok &= ok - 1ull;
                int sj = __shfl(s, j);
                int ej = __shfl(e, j);
                // symmetric partial-overlap (crossing) of my span vs span j
                bool crj = (s < sj && sj <= e && e < ej) ||
                           (sj < s && s <= ej && ej < e);
                unsigned long long cm = __ballot(crj);
                if ((cm & taken) == 0ull) {
                    taken |= (1ull << j);
                    ++n;
                    if (n >= KOUT) break;
                }
            }
            if (taken) {
                if ((taken >> lane) & 1ull) {
                    int slot = nbase + __popcll(taken & ((1ull << lane) - 1ull));
                    sel_idx[slot] = (int)id[t];
                    sel_se[slot] = se;
                    atomicMax(&le[s], e);
                    atomicMin(&es[e], s);
                }
                __threadfence_block();  // updates visible to next chunk's reads
            }
        }
        if (lane == 0) nshare = n;
    }
    __syncthreads();

    const int nsel = nshare;
    // build final sort keys: (start*287+end)<<7 | slot (stable on ties)
    if (tid < KOUT) {
        if (tid < nsel) {
            unsigned se = sel_se[tid];
            int s = (int)(se & 0xFFFFu);
            int e = (int)(se >> 16);
            skey[tid] = ((unsigned)(s * PADV + e) << 7) | (unsigned)tid;
        } else {
            skey[tid] = 0x7F000000u | (unsigned)tid;
        }
    }
    // bitonic 128 ascending
    for (int k = 2; k <= KOUT; k <<= 1) {
        for (int j = k >> 1; j > 0; j >>= 1) {
            __syncthreads();
            if (tid < KOUT) {
                int t = tid, p = t ^ j;
                if (p > t) {
                    unsigned a = skey[t], b = skey[p];
                    bool up = ((t & k) == 0);
                    if ((a > b) == up) { skey[t] = b; skey[p] = a; }
                }
            }
        }
    }
    __syncthreads();
    if (tid < KOUT) {
        int oslot = (int)(skey[tid] & 127u);
        int slot0 = (int)(skey[0] & 127u);
        int oi = (tid < nsel) ? sel_idx[oslot] : sel_idx[slot0];
        out_idx[l * KOUT + tid] = (float)oi;   // harness reads d_out as float32
        out_sc[l * KOUT + tid] = scores[base + oi];
    }
}

// ---------------------------------------------------------------------------
extern "C" void kernel_launch(void* const* d_in, const int* in_sizes, int n_in,
                              void* d_out, int out_size, void* d_ws, size_t ws_size,
                              hipStream_t stream) {
    const float* emb = (const float*)d_in[0];
    const float* w1  = (const float*)d_in[1];
    const float* b1  = (const float*)d_in[2];
    const float* w2  = (const float*)d_in[3];
    const float* b2  = (const float*)d_in[4];
    const int*   cs  = (const int*)d_in[5];
    const int*   ce  = (const int*)d_in[6];

    float* ws_scores = (float*)d_ws;                    // 57344 floats (229 KB)
    float* ws_w1t    = (float*)((char*)d_ws + 262144);  // 150*2304 floats (1.35 MB)

    k_transpose<<<dim3(1350), dim3(256), 0, stream>>>(w1, ws_w1t);
    k_scores<<<dim3((LSEG * NCAND) / MTILE), dim3(256), 0, stream>>>(
        emb, ws_w1t, b1, w2, b2, ws_scores);
    k_extract<<<dim3(LSEG), dim3(1024), 0, stream>>>(
        ws_scores, cs, ce, (float*)d_out, (float*)d_out + LSEG * KOUT);
}